// Round 7
// baseline (344.425 us; speedup 1.0000x reference)
//
#include <hip/hip_runtime.h>
#include <hip/hip_bf16.h>

// PointProp for MI355X (gfx950) — R11.
//   kP: prep (Wc = W0r@Wu@Wm folded; bias chain)     kC: pack weights (bf16)
//   kF: WAVE-LOCAL 2-TILE PIPELINE. Each wave owns two 16-row tiles.
//       Tile0 csum streamed in a prologue burst (ring-6 in-flight, 268MB
//       chip-wide, HBM-saturated); during tile0's ENTIRE MLP the wave streams
//       tile1's comp (2-3 pair-loads/phase, lag-2 ring consume) into 64 f32
//       acc VGPRs. csum never materialized (saves 67MB round-trip). L1 runs
//       csum-chunks FIRST so csacc regs die at the tile boundary (VGPR cap).
//       No barriers, no cross-block sync (R8 lesson), coalesced comp loads
//       (R9 lesson), stream spread over ~75% of wave lifetime (R6/R7 lesson).
// Math: out = L4(relu(L3(relu(L2(relu(sig@W0s^T + csum@Wc^T + bias1))))))
// with Wc = W0r@Wu@Wm folded (linearity), H padded 132->160.

typedef float  f32x4  __attribute__((ext_vector_type(4)));
typedef __bf16 bf16x8 __attribute__((ext_vector_type(8)));
typedef unsigned int   u32x2 __attribute__((ext_vector_type(2)));
typedef unsigned int   u32x4 __attribute__((ext_vector_type(4)));
typedef unsigned short u16x8 __attribute__((ext_vector_type(8)));

__device__ __forceinline__ unsigned short f2bf(float f) {
  unsigned int u = __builtin_bit_cast(unsigned int, f);
  u += 0x7fffu + ((u >> 16) & 1u);   // RNE
  return (unsigned short)(u >> 16);
}

__device__ __forceinline__ u32x2 pack4(f32x4 v) {
  u32x2 r;
  r[0] = (unsigned)f2bf(v[0]) | ((unsigned)f2bf(v[1]) << 16);
  r[1] = (unsigned)f2bf(v[2]) | ((unsigned)f2bf(v[3]) << 16);
  return r;
}

// ---------------- Kernel P: all prep (Wc, bias1, padded biases) -------------
__global__ __launch_bounds__(256) void kP(
    const float* __restrict__ W0, const float* __restrict__ Wu,
    const float* __restrict__ Wm, const float* __restrict__ bm,
    const float* __restrict__ bu, const float* __restrict__ b0,
    const float* __restrict__ b1, const float* __restrict__ b2,
    float* __restrict__ Wc, float* __restrict__ bias1,
    float* __restrict__ b1p, float* __restrict__ b2p) {
  const int b = blockIdx.x;
  const int d = threadIdx.x;
  if (b < 132) {
    __shared__ float u[256];
    const int h = b;
    float s = 0.f;
#pragma unroll 8
    for (int i = 0; i < 256; ++i) s += W0[h * 512 + 256 + i] * Wu[i * 256 + d];
    u[d] = s;
    __syncthreads();
    float s2 = 0.f;
#pragma unroll 8
    for (int j = 0; j < 256; ++j) s2 += u[j] * Wm[j * 256 + d];
    Wc[h * 256 + d] = s2;
  } else {
    __shared__ float bml[256];
    __shared__ float rbl[256];
    bml[d] = bm[d];
    __syncthreads();
    {
      const f32x4* wr = (const f32x4*)(Wu + d * 256);
      const f32x4* bm4 = (const f32x4*)bml;
      float s = 0.f;
#pragma unroll 8
      for (int i = 0; i < 64; ++i) {
        f32x4 w = wr[i], v = bm4[i];
        s += w[0] * v[0] + w[1] * v[1] + w[2] * v[2] + w[3] * v[3];
      }
      rbl[d] = 8.f * s + bu[d];
    }
    __syncthreads();
    if (d < 160) {
      float v = 0.f;
      if (d < 132) {
        float s = 0.f;
#pragma unroll 8
        for (int j = 0; j < 256; ++j) s += W0[d * 512 + 256 + j] * rbl[j];
        v = b0[d] + s;
      }
      bias1[d] = v;
      b1p[d] = (d < 132) ? b1[d] : 0.f;
      b2p[d] = (d < 132) ? b2[d] : 0.f;
    }
  }
}

// ---------------- Kernel C: pack weights to MFMA B-frag order (bf16) --------
// Chunk (kk,nt) = 1024B: lane l holds B[kk*32+(l>>4)*8+j][nt*16+(l&15)], j=0..7.
// L1: K=512,N=160; L2/L3: 160x160; L4: 160x256. P1..P4 CONTIGUOUS in ws
// (chunk c at c*10240 for c=0..25; L4 (kk,h) 8-frag group at
//  266240 + kk*16384 + h*8192).
__global__ __launch_bounds__(256) void kC(
    const float* __restrict__ W0, const float* __restrict__ Wc,
    const float* __restrict__ W1, const float* __restrict__ W2,
    const float* __restrict__ W3,
    unsigned short* __restrict__ P1, unsigned short* __restrict__ P2,
    unsigned short* __restrict__ P3, unsigned short* __restrict__ P4) {
  int e = blockIdx.x * 256 + threadIdx.x;
  if (e >= 174080) return;
  unsigned short* dst; int NT, rel, mode;
  if (e < 81920)       { dst = P1; NT = 10; rel = e;          mode = 0; }
  else if (e < 107520) { dst = P2; NT = 10; rel = e - 81920;  mode = 1; }
  else if (e < 133120) { dst = P3; NT = 10; rel = e - 107520; mode = 2; }
  else                 { dst = P4; NT = 16; rel = e - 133120; mode = 3; }
  int chunk = rel >> 9, q = rel & 511;
  int lane = q >> 3, j = q & 7;
  int kk = chunk / NT, nt = chunk - kk * NT;
  int k = kk * 32 + (lane >> 4) * 8 + j;
  int n = nt * 16 + (lane & 15);
  float v = 0.f;
  if (mode == 0) {
    if (n < 132) v = (k < 256) ? W0[n * 512 + k] : Wc[n * 256 + (k - 256)];
  } else if (mode == 1) {
    if (n < 132 && k < 132) v = W1[n * 132 + k];
  } else if (mode == 2) {
    if (n < 132 && k < 132) v = W2[n * 132 + k];
  } else {
    if (k < 132) v = W3[n * 132 + k];
  }
  dst[rel] = f2bf(v);
}

// ---- per-wave weight issue (direct L2 -> VGPR, coalesced 1KB per frag) ----
#define WISS(BUF, CHUNK)                                                     \
  {                                                                          \
    _Pragma("unroll") for (int nt = 0; nt < 10; ++nt)                        \
        BUF[nt] = *(const bf16x8*)(Pb + (CHUNK) * 10240 + nt * 1024 +        \
                                   lane * 16);                               \
  }
#define WISS8L4(BUF, Q)                                                      \
  {                                                                          \
    _Pragma("unroll") for (int nt = 0; nt < 8; ++nt)                         \
        BUF[nt] = *(const bf16x8*)(Pb + 266240 + ((Q) % 5) * 16384 +         \
                                   ((Q) / 5) * 8192 + nt * 1024 + lane * 16);\
  }
#define MFMA10(ACC, BUF, AF)                                                 \
  {                                                                          \
    _Pragma("unroll") for (int nt = 0; nt < 10; ++nt)                        \
        ACC[nt] = __builtin_amdgcn_mfma_f32_16x16x32_bf16(AF, BUF[nt],       \
                                                          ACC[nt], 0, 0, 0); \
  }

// stream schedule: pair count per phase f (0..27): 3,3,...(8x), then 2.
__device__ constexpr int SS(int f) {
  return (f <= 0) ? 0 : (f < 8 ? 3 * f : (f < 28 ? 24 + 2 * (f - 8) : 64));
}
// consume pairs issued 2 phases ago, then issue this phase's (ring-6).
#define SCONSUME(PHI)                                                        \
  {                                                                          \
    _Pragma("unroll") for (int pi = SS((PHI) - 2); pi < SS((PHI) - 1); ++pi){\
      csa[pi >> 3] += pend[pi % 6][0];                                       \
      csb[pi >> 3] += pend[pi % 6][1];                                       \
    }                                                                        \
  }
#define SISSUE(PHI)                                                          \
  {                                                                          \
    _Pragma("unroll") for (int pi = SS(PHI); pi < SS((PHI) + 1); ++pi) {     \
      const size_t ci = (size_t)(pi & 7) * 4194304u + nbase +                \
                        (size_t)(pi >> 3) * 128;                             \
      pend[pi % 6][0] = cp[ci];                                              \
      pend[pi % 6][1] = cp[ci + 1];                                          \
    }                                                                        \
  }
#define SSTEP(PHI) { SCONSUME(PHI); SISSUE(PHI); }

// write csum accumulators -> act tile (bf16, swizzled; layout == R10 cs write)
#define WCS()                                                                \
  {                                                                          \
    asm volatile("" ::: "memory");                                           \
    _Pragma("unroll") for (int j = 0; j < 8; ++j) {                          \
      const int rw = 2 * j + r2;                                             \
      u32x2 lo = pack4(csa[j]), hi = pack4(csb[j]);                          \
      *(u32x4*)(act + rw * 512 + ((c32 * 16) ^ ((rw & 7) << 4))) =           \
          u32x4{lo[0], lo[1], hi[0], hi[1]};                                 \
    }                                                                        \
    asm volatile("" ::: "memory");                                           \
  }
// bias+relu -> act
#define BIASRELU(BIASP)                                                      \
  {                                                                          \
    float bv[10];                                                            \
    _Pragma("unroll") for (int nt = 0; nt < 10; ++nt)                        \
        bv[nt] = (BIASP)[nt * 16 + l16];                                     \
    asm volatile("" ::: "memory");                                           \
    _Pragma("unroll") for (int nt = 0; nt < 10; ++nt) {                      \
      _Pragma("unroll") for (int r = 0; r < 4; ++r) {                        \
        const int row = lhalf * 4 + r;                                       \
        float v = fmaxf(acc[nt][r] + bv[nt], 0.f);                           \
        *(unsigned short*)(act + row * 512 +                                 \
                           (((nt * 16 + l16) * 2) ^ ((row & 7) << 4))) =     \
            f2bf(v);                                                         \
      }                                                                      \
    }                                                                        \
    asm volatile("" ::: "memory");                                           \
  }

// ---------------- Kernel F: fused 2-tile pipelined comp-sum + MLP -----------
// grid 512 x 256; wave w of block b owns tiles 2*(b*4+w) and +1 (16 rows ea).
// Per tile (36 phases): passA csum chunks 8..15, [pack sig], passB sig chunks
// 0..7, bias1, L2 16..20, L3 21..25, L4 10 half-phases. Weight dbuf wA/wB
// (w4A/w4B for L4) from L2, prefetched 1 phase ahead, continuous across tiles.
__global__ __launch_bounds__(256, 2) void kF(
    const float* __restrict__ signal, const float* __restrict__ comp,
    const unsigned short* __restrict__ Pseq,
    const float* __restrict__ bias1, const float* __restrict__ b1p,
    const float* __restrict__ b2p, const float* __restrict__ b3,
    float* __restrict__ out) {
  extern __shared__ char lds[];
  const int tid = threadIdx.x;
  const int wave = tid >> 6;
  const int lane = tid & 63;
  const int lhalf = lane >> 4;
  const int l16 = lane & 15;
  const int r2 = lane >> 5, c32 = lane & 31;
  char* act = lds + wave * 8192;
  const char* Pb = (const char*)Pseq;
  const int gid = (int)blockIdx.x * 4 + wave;   // 0..2047
  const int row0 = gid * 32;                    // tile0 rows [row0, row0+16)
  const int row1 = row0 + 16;                   // tile1 rows
  const int asw = (l16 & 7) << 4;
  const f32x4* sp = (const f32x4*)signal;
  const f32x4* cp = (const f32x4*)comp;
  const size_t base0 = (size_t)(row0 + r2) * 64 + c32 * 2;
  const size_t nbase = (size_t)(row1 + r2) * 64 + c32 * 2;

  bf16x8 wA[10], wB[10], w4A[8], w4B[8];
  f32x4 csa[8], csb[8], pend[6][2];
  f32x4 acc[10];
  f32x4 sg[16];

  // ================= prologue: tile0 csum burst + sig0 + chunk8 =============
  WISS(wA, 8);
#pragma unroll
  for (int r = 0; r < 16; ++r) sg[r] = sp[(size_t)(row0 + r) * 64 + lane];
#pragma unroll
  for (int j = 0; j < 8; ++j) {
    csa[j] = f32x4{0.f, 0.f, 0.f, 0.f};
    csb[j] = f32x4{0.f, 0.f, 0.f, 0.f};
  }
#pragma unroll
  for (int pi = 0; pi < 70; ++pi) {           // ring-6 burst, consume-then-issue
    if (pi >= 6) {
      const int q = pi - 6;
      csa[q >> 3] += pend[q % 6][0];
      csb[q >> 3] += pend[q % 6][1];
    }
    if (pi < 64) {
      const size_t ci =
          (size_t)(pi & 7) * 4194304u + base0 + (size_t)(pi >> 3) * 128;
      pend[pi % 6][0] = cp[ci];
      pend[pi % 6][1] = cp[ci + 1];
    }
  }
  WCS();                                       // csum0 -> act
#pragma unroll
  for (int j = 0; j < 8; ++j) {                // reset for tile1 stream
    csa[j] = f32x4{0.f, 0.f, 0.f, 0.f};
    csb[j] = f32x4{0.f, 0.f, 0.f, 0.f};
  }

  // ================= TILE 0 (streams tile1) =================
#pragma unroll
  for (int i = 0; i < 10; ++i) acc[i] = f32x4{0.f, 0.f, 0.f, 0.f};
  // passA: csum chunks 8..15 (ph 0..7)
#pragma unroll
  for (int ph = 0; ph < 8; ++ph) {
    const int cn = (ph < 7) ? (9 + ph) : 0;    // next chunk (after 15 -> 0)
    if ((ph + 1) & 1) { WISS(wB, cn); } else { WISS(wA, cn); }
    bf16x8 af =
        *(const bf16x8*)(act + l16 * 512 + ((ph * 64 + lhalf * 16) ^ asw));
    if (ph & 1) { MFMA10(acc, wB, af); } else { MFMA10(acc, wA, af); }
  }
  // pack sig0 -> act
  asm volatile("" ::: "memory");
#pragma unroll
  for (int r = 0; r < 16; ++r)
    *(u32x2*)(act + r * 512 + ((lane * 8) ^ ((r & 7) << 4))) = pack4(sg[r]);
  asm volatile("" ::: "memory");
  // passB: sig chunks 0..7 (ph 8..15), stream f=0..7
#pragma unroll
  for (int ph = 8; ph < 16; ++ph) {
    const int f = ph - 8;
    SSTEP(f);
    const int cn = (ph < 15) ? (f + 1) : 16;
    if ((ph + 1) & 1) { WISS(wB, cn); } else { WISS(wA, cn); }
    bf16x8 af =
        *(const bf16x8*)(act + l16 * 512 + ((f * 64 + lhalf * 16) ^ asw));
    if (ph & 1) { MFMA10(acc, wB, af); } else { MFMA10(acc, wA, af); }
  }
  BIASRELU(bias1);
  // L2 (chunks 16..20, ph 16..20, f 8..12), L3 (21..25, ph 21..25, f 13..17)
#pragma unroll
  for (int L = 0; L < 2; ++L) {
#pragma unroll
    for (int i = 0; i < 10; ++i) acc[i] = f32x4{0.f, 0.f, 0.f, 0.f};
#pragma unroll
    for (int q = 0; q < 5; ++q) {
      const int ph = 16 + L * 5 + q;
      const int f = ph - 8;
      const int cc = 16 + L * 5 + q;
      SSTEP(f);
      if (cc < 25) {
        if ((ph + 1) & 1) { WISS(wB, cc + 1); } else { WISS(wA, cc + 1); }
      } else {
        WISS8L4(w4A, 0);
      }
      bf16x8 af =
          *(const bf16x8*)(act + l16 * 512 + ((q * 64 + lhalf * 16) ^ asw));
      if (ph & 1) { MFMA10(acc, wB, af); } else { MFMA10(acc, wA, af); }
    }
    if (L) { BIASRELU(b2p); } else { BIASRELU(b1p); }
  }
  // L4: halves H=0,1 x kk=0..4 (ph 26..35, f 18..27)
#pragma unroll
  for (int H = 0; H < 2; ++H) {
    f32x4 a4[8];
#pragma unroll
    for (int i = 0; i < 8; ++i) a4[i] = f32x4{0.f, 0.f, 0.f, 0.f};
#pragma unroll
    for (int kk = 0; kk < 5; ++kk) {
      const int q = H * 5 + kk;
      const int f = 18 + q;
      SSTEP(f);
      if (q < 9) {
        if (q & 1) { WISS8L4(w4A, q + 1); } else { WISS8L4(w4B, q + 1); }
      } else {
        WISS(wA, 8);                           // tile1 passA chunk 8
      }
      bf16x8 af =
          *(const bf16x8*)(act + l16 * 512 + ((kk * 64 + lhalf * 16) ^ asw));
#pragma unroll
      for (int i = 0; i < 8; ++i) {
        if (q & 1)
          a4[i] = __builtin_amdgcn_mfma_f32_16x16x32_bf16(af, w4B[i], a4[i],
                                                          0, 0, 0);
        else
          a4[i] = __builtin_amdgcn_mfma_f32_16x16x32_bf16(af, w4A[i], a4[i],
                                                          0, 0, 0);
      }
    }
    float bv[8];
#pragma unroll
    for (int i = 0; i < 8; ++i) bv[i] = b3[(H * 8 + i) * 16 + l16];
    float* op = out + (size_t)(row0 + lhalf * 4) * 256 + H * 128 + l16;
#pragma unroll
    for (int i = 0; i < 8; ++i) {
#pragma unroll
      for (int r = 0; r < 4; ++r)
        op[(size_t)r * 256 + i * 16] = a4[i][r] + bv[i];
    }
  }
  // drain stream (pairs 60..63)
  SCONSUME(28);
  SCONSUME(29);

  // ================= TILE 1 (no stream) =================
  WCS();                                       // csum1 -> act
#pragma unroll
  for (int i = 0; i < 10; ++i) acc[i] = f32x4{0.f, 0.f, 0.f, 0.f};
  // passA: csum chunks 8..15; weave sig1 loads (2 rows/phase)
#pragma unroll
  for (int ph = 0; ph < 8; ++ph) {
    sg[2 * ph] = sp[(size_t)(row1 + 2 * ph) * 64 + lane];
    sg[2 * ph + 1] = sp[(size_t)(row1 + 2 * ph + 1) * 64 + lane];
    const int cn = (ph < 7) ? (9 + ph) : 0;
    if ((ph + 1) & 1) { WISS(wB, cn); } else { WISS(wA, cn); }
    bf16x8 af =
        *(const bf16x8*)(act + l16 * 512 + ((ph * 64 + lhalf * 16) ^ asw));
    if (ph & 1) { MFMA10(acc, wB, af); } else { MFMA10(acc, wA, af); }
  }
  // pack sig1 -> act
  asm volatile("" ::: "memory");
#pragma unroll
  for (int r = 0; r < 16; ++r)
    *(u32x2*)(act + r * 512 + ((lane * 8) ^ ((r & 7) << 4))) = pack4(sg[r]);
  asm volatile("" ::: "memory");
  // passB: sig chunks 0..7
#pragma unroll
  for (int ph = 8; ph < 16; ++ph) {
    const int f = ph - 8;
    const int cn = (ph < 15) ? (f + 1) : 16;
    if ((ph + 1) & 1) { WISS(wB, cn); } else { WISS(wA, cn); }
    bf16x8 af =
        *(const bf16x8*)(act + l16 * 512 + ((f * 64 + lhalf * 16) ^ asw));
    if (ph & 1) { MFMA10(acc, wB, af); } else { MFMA10(acc, wA, af); }
  }
  BIASRELU(bias1);
#pragma unroll
  for (int L = 0; L < 2; ++L) {
#pragma unroll
    for (int i = 0; i < 10; ++i) acc[i] = f32x4{0.f, 0.f, 0.f, 0.f};
#pragma unroll
    for (int q = 0; q < 5; ++q) {
      const int ph = 16 + L * 5 + q;
      const int cc = 16 + L * 5 + q;
      if (cc < 25) {
        if ((ph + 1) & 1) { WISS(wB, cc + 1); } else { WISS(wA, cc + 1); }
      } else {
        WISS8L4(w4A, 0);
      }
      bf16x8 af =
          *(const bf16x8*)(act + l16 * 512 + ((q * 64 + lhalf * 16) ^ asw));
      if (ph & 1) { MFMA10(acc, wB, af); } else { MFMA10(acc, wA, af); }
    }
    if (L) { BIASRELU(b2p); } else { BIASRELU(b1p); }
  }
#pragma unroll
  for (int H = 0; H < 2; ++H) {
    f32x4 a4[8];
#pragma unroll
    for (int i = 0; i < 8; ++i) a4[i] = f32x4{0.f, 0.f, 0.f, 0.f};
#pragma unroll
    for (int kk = 0; kk < 5; ++kk) {
      const int q = H * 5 + kk;
      if (q < 9) {
        if (q & 1) { WISS8L4(w4A, q + 1); } else { WISS8L4(w4B, q + 1); }
      }
      bf16x8 af =
          *(const bf16x8*)(act + l16 * 512 + ((kk * 64 + lhalf * 16) ^ asw));
#pragma unroll
      for (int i = 0; i < 8; ++i) {
        if (q & 1)
          a4[i] = __builtin_amdgcn_mfma_f32_16x16x32_bf16(af, w4B[i], a4[i],
                                                          0, 0, 0);
        else
          a4[i] = __builtin_amdgcn_mfma_f32_16x16x32_bf16(af, w4A[i], a4[i],
                                                          0, 0, 0);
      }
    }
    float bv[8];
#pragma unroll
    for (int i = 0; i < 8; ++i) bv[i] = b3[(H * 8 + i) * 16 + l16];
    float* op = out + (size_t)(row1 + lhalf * 4) * 256 + H * 128 + l16;
#pragma unroll
    for (int i = 0; i < 8; ++i) {
#pragma unroll
      for (int r = 0; r < 4; ++r)
        op[(size_t)r * 256 + i * 16] = a4[i][r] + bv[i];
    }
  }
}

// ---------------- launcher ----------------
extern "C" void kernel_launch(void* const* d_in, const int* in_sizes, int n_in,
                              void* d_out, int out_size, void* d_ws, size_t ws_size,
                              hipStream_t stream) {
  const float* signal = (const float*)d_in[0];
  const float* comp   = (const float*)d_in[1];
  const float* Wm = (const float*)d_in[2];
  const float* bm = (const float*)d_in[3];
  const float* Wu = (const float*)d_in[4];
  const float* bu = (const float*)d_in[5];
  const float* W0 = (const float*)d_in[6];
  const float* b0 = (const float*)d_in[7];
  const float* W1 = (const float*)d_in[8];
  const float* b1 = (const float*)d_in[9];
  const float* W2 = (const float*)d_in[10];
  const float* b2 = (const float*)d_in[11];
  const float* W3 = (const float*)d_in[12];
  const float* b3 = (const float*)d_in[13];

  char* ws = (char*)d_ws;
  float* Wc    = (float*)(ws + 0);        // 33792 f32 (135168 B)
  float* bias1 = (float*)(ws + 135168);   // 160 f32
  float* b1p   = (float*)(ws + 135808);   // 160 f32
  float* b2p   = (float*)(ws + 136448);   // 160 f32
  // contiguous packed-weight sequence (uniform chunk offsets off P1):
  unsigned short* P1 = (unsigned short*)(ws + 137216);  // 81920 u16 (160KB)
  unsigned short* P2 = (unsigned short*)(ws + 301056);  // 25600 u16 (50KB)
  unsigned short* P3 = (unsigned short*)(ws + 352256);  // 25600 u16 (50KB)
  unsigned short* P4 = (unsigned short*)(ws + 403456);  // 40960 u16 (80KB)

  hipLaunchKernelGGL(kP, dim3(133), dim3(256), 0, stream,
                     W0, Wu, Wm, bm, bu, b0, b1, b2, Wc, bias1, b1p, b2p);
  hipLaunchKernelGGL(kC, dim3(680), dim3(256), 0, stream,
                     W0, Wc, W1, W2, W3, P1, P2, P3, P4);
  hipLaunchKernelGGL(kF, dim3(512), dim3(256), 32768, stream,
                     signal, comp, P1, bias1, b1p, b2p, b3, (float*)d_out);
}

// Round 8
// 199.971 us; speedup vs baseline: 1.7224x; 1.7224x over previous
//
#include <hip/hip_runtime.h>
#include <hip/hip_bf16.h>

// PointProp for MI355X (gfx950) — R12.
//   kA: prep1 + comp-sum (k-serial, R10 verbatim — BW-bound ~91us)
//   kB: prep2 (verbatim)   kC: pack weights (verbatim)
//   kD: R10 structure, 16 rows/wave (was 32). Dropping the second row-group
//       cuts live VGPRs from ~220 to ~155 (acc 40 + wA/wB 80 + cs 16 + misc)
//       -> __launch_bounds__(256,3) fits WITHOUT spilling -> 3 waves/SIMD,
//       3 blocks/CU (32KB LDS each), 12 waves/CU: 1.5x the latency hiding
//       for the per-phase 10-load L2 WISS batch that R10 stalled on at
//       2 waves/SIMD. Weight L2 traffic doubles to 1.4GB (~25 TB/s agg,
//       under the 34.5 ceiling; 12 co-paced waves/CU hit L1 for repeats).
//       R5/R8/R11 lessons kept: no cross-block sync, no >230-VGPR live sets.
// Math: out = L4(relu(L3(relu(L2(relu(sig@W0s^T + csum@Wc^T + bias1))))))
// with Wc = W0r@Wu@Wm folded (linearity), H padded 132->160.

typedef float  f32x4  __attribute__((ext_vector_type(4)));
typedef __bf16 bf16x8 __attribute__((ext_vector_type(8)));
typedef unsigned int   u32x2 __attribute__((ext_vector_type(2)));
typedef unsigned short u16x8 __attribute__((ext_vector_type(8)));

__device__ __forceinline__ unsigned short f2bf(float f) {
  unsigned int u = __builtin_bit_cast(unsigned int, f);
  u += 0x7fffu + ((u >> 16) & 1u);   // RNE
  return (unsigned short)(u >> 16);
}

__device__ __forceinline__ u32x2 pack4(f32x4 v) {
  u32x2 r;
  r[0] = (unsigned)f2bf(v[0]) | ((unsigned)f2bf(v[1]) << 16);
  r[1] = (unsigned)f2bf(v[2]) | ((unsigned)f2bf(v[3]) << 16);
  return r;
}

__device__ __forceinline__ float wave_reduce(float s) {
#pragma unroll
  for (int m = 32; m > 0; m >>= 1) s += __shfl_xor(s, m, 64);
  return s;
}

// ---------------- Kernel A: prep1 (U, rb) + comp-sum (k-serial) -------------
// blocks 0..131: U = W0r@Wu ; 132..195: rb = 8*(Wu@bm)+bu
// blocks 196..2243: block cb owns rows [cb*32, cb*32+32); k-serial.
__global__ __launch_bounds__(256) void kA(const float* __restrict__ comp,
                                          const float* __restrict__ W0,
                                          const float* __restrict__ Wu,
                                          const float* __restrict__ bm,
                                          const float* __restrict__ bu,
                                          float* __restrict__ U,
                                          float* __restrict__ rb,
                                          unsigned short* __restrict__ csum) {
  const int b = blockIdx.x;
  if (b >= 196) {
    const int cb = b - 196;                       // 0..2047
    const int t = threadIdx.x;
    const f32x4* cp = (const f32x4*)comp;
    const size_t base = (size_t)cb * 2048 + t;    // f32x4 units
    f32x4 a[8];
#pragma unroll
    for (int j = 0; j < 8; ++j) a[j] = cp[base + j * 256];
#pragma unroll
    for (int k = 1; k < 8; ++k) {
      f32x4 t0[8];
#pragma unroll
      for (int j = 0; j < 8; ++j) t0[j] = cp[base + (size_t)k * 4194304u + j * 256];
#pragma unroll
      for (int j = 0; j < 8; ++j) a[j] += t0[j];
    }
    u32x2* op = (u32x2*)csum;
#pragma unroll
    for (int j = 0; j < 8; ++j) op[base + j * 256] = pack4(a[j]);
  } else if (b < 132) {
    const int h = b, d = threadIdx.x;
    float s = 0.f;
#pragma unroll 8
    for (int i = 0; i < 256; ++i) s += W0[h * 512 + 256 + i] * Wu[i * 256 + d];
    U[h * 256 + d] = s;
  } else {
    const int t = (b - 132) * 4 + (threadIdx.x >> 6);   // 0..255
    const int lane = threadIdx.x & 63;
    f32x4 w = ((const f32x4*)(Wu + t * 256))[lane];
    f32x4 v = ((const f32x4*)bm)[lane];
    float s = w[0] * v[0] + w[1] * v[1] + w[2] * v[2] + w[3] * v[3];
    s = wave_reduce(s);
    if (lane == 0) rb[t] = 8.f * s + bu[t];
  }
}

// ---------------- Kernel B: prep2 (Wc, bias1, padded biases) ----------------
__global__ __launch_bounds__(256) void kB(const float* __restrict__ U,
                                          const float* __restrict__ Wm,
                                          const float* __restrict__ W0,
                                          const float* __restrict__ rb,
                                          const float* __restrict__ b0,
                                          const float* __restrict__ b1,
                                          const float* __restrict__ b2,
                                          float* __restrict__ Wc,
                                          float* __restrict__ bias1,
                                          float* __restrict__ b1p,
                                          float* __restrict__ b2p) {
  const int b = blockIdx.x;
  if (b < 132) {
    const int h = b, d = threadIdx.x;
    float s = 0.f;
#pragma unroll 8
    for (int j = 0; j < 256; ++j) s += U[h * 256 + j] * Wm[j * 256 + d];
    Wc[h * 256 + d] = s;
  } else {
    const int t = (b - 132) * 4 + (threadIdx.x >> 6);   // 0..159
    const int lane = threadIdx.x & 63;
    float v = 0.f;
    if (t < 132) {
      f32x4 w = ((const f32x4*)(W0 + t * 512 + 256))[lane];
      f32x4 r4 = ((const f32x4*)rb)[lane];
      float s = w[0] * r4[0] + w[1] * r4[1] + w[2] * r4[2] + w[3] * r4[3];
      s = wave_reduce(s);
      v = b0[t] + s;
    }
    if (lane == 0) {
      bias1[t] = v;
      b1p[t] = (t < 132) ? b1[t] : 0.f;
      b2p[t] = (t < 132) ? b2[t] : 0.f;
    }
  }
}

// ---------------- Kernel C: pack weights to MFMA B-frag order (bf16) --------
// Chunk (kk,nt) = 1024B: lane l holds B[kk*32+(l>>4)*8+j][nt*16+(l&15)], j=0..7.
// L1: K=512,N=160; L2/L3: 160x160; L4: 160x256. P1..P4 CONTIGUOUS in ws.
__global__ __launch_bounds__(256) void kC(
    const float* __restrict__ W0, const float* __restrict__ Wc,
    const float* __restrict__ W1, const float* __restrict__ W2,
    const float* __restrict__ W3,
    unsigned short* __restrict__ P1, unsigned short* __restrict__ P2,
    unsigned short* __restrict__ P3, unsigned short* __restrict__ P4) {
  int e = blockIdx.x * 256 + threadIdx.x;
  if (e >= 174080) return;
  unsigned short* dst; int NT, rel, mode;
  if (e < 81920)       { dst = P1; NT = 10; rel = e;          mode = 0; }
  else if (e < 107520) { dst = P2; NT = 10; rel = e - 81920;  mode = 1; }
  else if (e < 133120) { dst = P3; NT = 10; rel = e - 107520; mode = 2; }
  else                 { dst = P4; NT = 16; rel = e - 133120; mode = 3; }
  int chunk = rel >> 9, q = rel & 511;
  int lane = q >> 3, j = q & 7;
  int kk = chunk / NT, nt = chunk - kk * NT;
  int k = kk * 32 + (lane >> 4) * 8 + j;
  int n = nt * 16 + (lane & 15);
  float v = 0.f;
  if (mode == 0) {
    if (n < 132) v = (k < 256) ? W0[n * 512 + k] : Wc[n * 256 + (k - 256)];
  } else if (mode == 1) {
    if (n < 132 && k < 132) v = W1[n * 132 + k];
  } else if (mode == 2) {
    if (n < 132 && k < 132) v = W2[n * 132 + k];
  } else {
    if (k < 132) v = W3[n * 132 + k];
  }
  dst[rel] = f2bf(v);
}

// ---- per-wave weight issue (direct L2/L1 -> VGPR, coalesced 1KB per frag) --
// chunks 0..25 contiguous at c*10240; L4 chunk (h,kk) 8-frag group at
// 266240 + kk*16384 + h*8192.
#define WISS(BUF, CHUNK)                                                     \
  {                                                                          \
    _Pragma("unroll") for (int nt = 0; nt < 10; ++nt)                        \
        BUF[nt] = *(const bf16x8*)(Pb + (CHUNK) * 10240 + nt * 1024 +        \
                                   lane * 16);                               \
  }
#define WISS8L4(BUF, Q)                                                      \
  {                                                                          \
    _Pragma("unroll") for (int nt = 0; nt < 8; ++nt)                         \
        BUF[nt] = *(const bf16x8*)(Pb + 266240 + ((Q) % 5) * 16384 +         \
                                   ((Q) / 5) * 8192 + nt * 1024 + lane * 16);\
  }
#define MFMA10(ACC, BUF, AF)                                                 \
  {                                                                          \
    _Pragma("unroll") for (int nt = 0; nt < 10; ++nt)                        \
        ACC[nt] = __builtin_amdgcn_mfma_f32_16x16x32_bf16(AF, BUF[nt],       \
                                                          ACC[nt], 0, 0, 0); \
  }

// ---------------- Kernel D: 4-layer MLP, 16 rows/wave, register weights -----
// grid 1024 x 256; wave owns 16 rows (act tile 8KB, wave-private, XOR-swz).
// launch_bounds(256,3): VGPR cap 170 -> 3 waves/SIMD, 3 blocks/CU (32KB LDS),
// 12 waves/CU. Steady live set ~155 VGPR (acc 40 + wA/wB 80 + cs 16 + misc).
__global__ __launch_bounds__(256, 3) void kD(
    const float* __restrict__ signal, const unsigned short* __restrict__ csum,
    const unsigned short* __restrict__ Pseq,
    const float* __restrict__ bias1, const float* __restrict__ b1p,
    const float* __restrict__ b2p, const float* __restrict__ b3,
    float* __restrict__ out) {
  extern __shared__ char lds[];
  const int tid = threadIdx.x;
  const int wave = tid >> 6;
  const int lane = tid & 63;
  const int lhalf = lane >> 4;
  const int l16 = lane & 15;
  const int r2 = lane >> 5, c32 = lane & 31;
  char* act = lds + wave * 8192;
  const char* Pb = (const char*)Pseq;
  const int row0 = ((int)blockIdx.x * 4 + wave) * 16;
  const int asw = (l16 & 7) << 4;
  const f32x4* sp = (const f32x4*)signal;

  // csum rows early (16 VGPR held until pass-2 switch; HBM latency hidden)
  u16x8 cs[8];
#pragma unroll
  for (int j = 0; j < 8; ++j)
    cs[j] = *(const u16x8*)(csum + (size_t)(row0 + 2 * j + r2) * 256 + c32 * 8);

  // signal -> act tile (bulk 16-row load; sg dies before the L1 peak)
  {
    f32x4 sg[16];
#pragma unroll
    for (int r = 0; r < 16; ++r) sg[r] = sp[(size_t)(row0 + r) * 64 + lane];
#pragma unroll
    for (int r = 0; r < 16; ++r)
      *(u32x2*)(act + r * 512 + ((lane * 8) ^ ((r & 7) << 4))) = pack4(sg[r]);
  }

  bf16x8 wA[10], wB[10];
  WISS(wA, 0);

  f32x4 acc[10];
#pragma unroll
  for (int i = 0; i < 10; ++i) acc[i] = f32x4{0.f, 0.f, 0.f, 0.f};

  // ---- L1 pass 1 (signal half), chunks 0..7 ----
#pragma unroll
  for (int kk = 0; kk < 8; ++kk) {
    if ((kk + 1) & 1) { WISS(wB, kk + 1); } else { WISS(wA, kk + 1); }
    bf16x8 af =
        *(const bf16x8*)(act + l16 * 512 + ((kk * 64 + lhalf * 16) ^ asw));
    if (kk & 1) { MFMA10(acc, wB, af); } else { MFMA10(acc, wA, af); }
  }

  // overwrite act tile with comp-sum (wave-local)
  asm volatile("" ::: "memory");
#pragma unroll
  for (int j = 0; j < 8; ++j) {
    const int rw = 2 * j + r2;
    *(u16x8*)(act + rw * 512 + ((c32 * 16) ^ ((rw & 7) << 4))) = cs[j];
  }
  asm volatile("" ::: "memory");

  // ---- L1 pass 2 (comp-sum half), chunks 8..15 ----
#pragma unroll
  for (int kk = 8; kk < 16; ++kk) {
    if ((kk + 1) & 1) { WISS(wB, kk + 1); } else { WISS(wA, kk + 1); }
    bf16x8 af = *(const bf16x8*)(act + l16 * 512 +
                                 (((kk - 8) * 64 + lhalf * 16) ^ asw));
    if (kk & 1) { MFMA10(acc, wB, af); } else { MFMA10(acc, wA, af); }
  }

  // bias + relu -> act
  {
    float bv[10];
#pragma unroll
    for (int nt = 0; nt < 10; ++nt) bv[nt] = bias1[nt * 16 + l16];
    asm volatile("" ::: "memory");
#pragma unroll
    for (int nt = 0; nt < 10; ++nt) {
#pragma unroll
      for (int r = 0; r < 4; ++r) {
        const int row = lhalf * 4 + r;
        float v = fmaxf(acc[nt][r] + bv[nt], 0.f);
        *(unsigned short*)(act + row * 512 +
                           (((nt * 16 + l16) * 2) ^ ((row & 7) << 4))) = f2bf(v);
      }
    }
    asm volatile("" ::: "memory");
  }

  // ---- hidden layers: chunks 16..20 (W1), 21..25 (W2) ----
  bf16x8 w4A[8], w4B[8];
#pragma unroll
  for (int L = 0; L < 2; ++L) {
    const float* hbias = L ? b2p : b1p;
#pragma unroll
    for (int i = 0; i < 10; ++i) acc[i] = f32x4{0.f, 0.f, 0.f, 0.f};
#pragma unroll
    for (int qq = 0; qq < 5; ++qq) {
      const int cc = 16 + L * 5 + qq;      // chunk in use (even->wA, odd->wB)
      if (cc < 25) {
        if (cc & 1) { WISS(wA, cc + 1); } else { WISS(wB, cc + 1); }
      } else {
        WISS8L4(w4A, 0);                   // prefetch L4 q=0
      }
      bf16x8 af =
          *(const bf16x8*)(act + l16 * 512 + ((qq * 64 + lhalf * 16) ^ asw));
      if (cc & 1) { MFMA10(acc, wB, af); } else { MFMA10(acc, wA, af); }
    }
    float bv[10];
#pragma unroll
    for (int nt = 0; nt < 10; ++nt) bv[nt] = hbias[nt * 16 + l16];
    asm volatile("" ::: "memory");
#pragma unroll
    for (int nt = 0; nt < 10; ++nt) {
#pragma unroll
      for (int r = 0; r < 4; ++r) {
        const int row = lhalf * 4 + r;
        float v = fmaxf(acc[nt][r] + bv[nt], 0.f);
        *(unsigned short*)(act + row * 512 +
                           (((nt * 16 + l16) * 2) ^ ((row & 7) << 4))) = f2bf(v);
      }
    }
    asm volatile("" ::: "memory");
  }

  // ---- layer 4: two N-128 halves h=0,1; q = h*5+kk (even->w4A, odd->w4B) --
#pragma unroll
  for (int h = 0; h < 2; ++h) {
    f32x4 a4[8];
#pragma unroll
    for (int i = 0; i < 8; ++i) a4[i] = f32x4{0.f, 0.f, 0.f, 0.f};
#pragma unroll
    for (int kk = 0; kk < 5; ++kk) {
      const int q = h * 5 + kk;
      if (q < 9) {
        if (q & 1) { WISS8L4(w4A, q + 1); } else { WISS8L4(w4B, q + 1); }
      }
      bf16x8 af =
          *(const bf16x8*)(act + l16 * 512 + ((kk * 64 + lhalf * 16) ^ asw));
#pragma unroll
      for (int i = 0; i < 8; ++i) {
        if (q & 1)
          a4[i] = __builtin_amdgcn_mfma_f32_16x16x32_bf16(af, w4B[i], a4[i],
                                                          0, 0, 0);
        else
          a4[i] = __builtin_amdgcn_mfma_f32_16x16x32_bf16(af, w4A[i], a4[i],
                                                          0, 0, 0);
      }
    }
    // store this half
    float bv[8];
#pragma unroll
    for (int i = 0; i < 8; ++i) bv[i] = b3[(h * 8 + i) * 16 + l16];
    float* op = out + (size_t)(row0 + lhalf * 4) * 256 + h * 128 + l16;
#pragma unroll
    for (int i = 0; i < 8; ++i) {
#pragma unroll
      for (int r = 0; r < 4; ++r)
        op[(size_t)r * 256 + i * 16] = a4[i][r] + bv[i];
    }
  }
}

// ---------------- launcher ----------------
extern "C" void kernel_launch(void* const* d_in, const int* in_sizes, int n_in,
                              void* d_out, int out_size, void* d_ws, size_t ws_size,
                              hipStream_t stream) {
  const float* signal = (const float*)d_in[0];
  const float* comp   = (const float*)d_in[1];
  const float* Wm = (const float*)d_in[2];
  const float* bm = (const float*)d_in[3];
  const float* Wu = (const float*)d_in[4];
  const float* bu = (const float*)d_in[5];
  const float* W0 = (const float*)d_in[6];
  const float* b0 = (const float*)d_in[7];
  const float* W1 = (const float*)d_in[8];
  const float* b1 = (const float*)d_in[9];
  const float* W2 = (const float*)d_in[10];
  const float* b2 = (const float*)d_in[11];
  const float* W3 = (const float*)d_in[12];
  const float* b3 = (const float*)d_in[13];

  char* ws = (char*)d_ws;
  float* U     = (float*)(ws + 0);        // 33792 f32
  float* Wc    = (float*)(ws + 135168);   // 33792 f32
  float* bias1 = (float*)(ws + 270336);   // 160 f32
  float* b1p   = (float*)(ws + 270976);   // 160 f32
  float* b2p   = (float*)(ws + 271616);   // 160 f32
  float* rb    = (float*)(ws + 272256);   // 256 f32
  // contiguous packed-weight sequence (stage chunks index off P1):
  unsigned short* P1 = (unsigned short*)(ws + 273408);  // 81920 u16 (160KB)
  unsigned short* P2 = (unsigned short*)(ws + 437248);  // 25600 u16 (50KB)
  unsigned short* P3 = (unsigned short*)(ws + 488448);  // 25600 u16 (50KB)
  unsigned short* P4 = (unsigned short*)(ws + 539648);  // 40960 u16 (80KB)
  unsigned short* csum = (unsigned short*)(ws + 621568); // [N,256] bf16, 33.5MB

  hipLaunchKernelGGL(kA, dim3(2244), dim3(256), 0, stream,
                     comp, W0, Wu, bm, bu, U, rb, csum);
  hipLaunchKernelGGL(kB, dim3(172), dim3(256), 0, stream,
                     U, Wm, W0, rb, b0, b1, b2, Wc, bias1, b1p, b2p);
  hipLaunchKernelGGL(kC, dim3(680), dim3(256), 0, stream,
                     W0, Wc, W1, W2, W3, P1, P2, P3, P4);
  hipLaunchKernelGGL(kD, dim3(1024), dim3(256), 32768, stream,
                     signal, csum, P1, bias1, b1p, b2p, b3, (float*)d_out);
}